// Round 8
// baseline (193.460 us; speedup 1.0000x reference)
//
#include <hip/hip_runtime.h>
#include <cmath>

// ---------------------------------------------------------------------------
// JPEG compress (YCbCr + 2x2 chroma pool + 8x8 DCT + quantize/round).
//
// Numerics contract (VERIFIED r4..r14, absmax 0.0): f32 end-to-end, every
// accumulation step is mul-then-add with TWO roundings (no FMA). Value-path
// ops are explicit v_mul_f32 / v_add_f32 / v_sub_f32 (asm). fdiv/rint are
// __fdiv_rn / rintf builtins (verified). First DCT step uses rn(0+x)=x.
//
// Recipe per output (DO NOT CHANGE):
//   t_c   = rn(x_c * 255)
//   y     = chain c=R,G,B: a = rn(a + rn(t_c*k_c));  X = rn(a - 128)
//   cb/cr = same chain + 128; pool ((p00+p01)+p10)+p11 * 0.25; - 128
//   dct_i = 64-step chain j=(x,y) row-major from 0: a = rn(a + rn(T_ij*X_j))
//   outv  = rintf( rn( rn(sc_i * dct_i) / q_i ) )
//
// R14->R15 (keep mega-asm; kill the two measured stall sources):
//  1. T-row s_loads were issued right before their lgkmcnt(0) -> K$ latency
//     fully exposed 32x/wave, and the WG's 4 waves stall in lockstep.
//     FIX: double-banked SGPR pipeline (A=s[36:67], B=s[68:99], each = one
//     16-float chunk of TWO rows). Per chunk: wait -> issue next chunk into
//     other bank -> 64-inst chain. Loads fly under the previous chain.
//  2. Single-acc chain = ~6cyc/MAC dep stalls. FIX: two outputs (rows 2p,
//     2p+1) interleaved mulA,mulB,addA,addB (temps v104/v105) -> 4cyc/MAC
//     full issue. Each output's j-order stays strictly ascending (exact
//     mandated rounding chain per output).
// Staging / slab-transpose stores / addressing: r14 verbatim (verified).
// ---------------------------------------------------------------------------

namespace jc {

constexpr double c1 = 0.98078528040323044912618223613424;
constexpr double c2 = 0.92387953251128675612818318939679;
constexpr double c3 = 0.83146961230254523707878837761791;
constexpr double c4 = 0.70710678118654752440084436210485;
constexpr double c5 = 0.55557023301960222474283081394853;
constexpr double c6 = 0.38268343236508977172845998403040;
constexpr double c7 = 0.19509032201612826784828486847702;
constexpr double alpha0 = 0.70710678118654746171979706919384;  // 1/sqrt(2)

struct Tab {
  float tr[4096];  // ROW-major: tr[i*64+j], i=(u,v), j=(x,y)
  float sc[64];
  float yq[64];
  float cq[64];
  constexpr Tab() : tr(), sc(), yq(), cq() {
    const double CX[8][8] = {
      {1.0,  c1,  c2,  c3,  c4,  c5,  c6,  c7},
      {1.0,  c3,  c6, -c7, -c4, -c1, -c2, -c5},
      {1.0,  c5, -c6, -c1, -c4,  c7,  c2,  c3},
      {1.0,  c7, -c2, -c5,  c4,  c3, -c6, -c1},
      {1.0, -c7, -c2,  c5,  c4, -c3, -c6,  c1},
      {1.0, -c5, -c6,  c1, -c4, -c7,  c2, -c3},
      {1.0, -c3,  c6,  c7, -c4,  c1, -c2,  c5},
      {1.0, -c1,  c2, -c3,  c4, -c5,  c6, -c7}};
    for (int i = 0; i < 64; ++i) {
      const int u = i >> 3, v = i & 7;
      for (int j = 0; j < 64; ++j) {
        const int x = j >> 3, y = j & 7;
        tr[i * 64 + j] = (float)(CX[x][u] * CX[y][v]);
      }
      const double au = (u == 0) ? alpha0 : 1.0;
      const double av = (v == 0) ? alpha0 : 1.0;
      sc[i] = (float)((au * av) * 0.25);
    }
    const int YT[64] = {
      16, 11, 10, 16, 24, 40, 51, 61,
      12, 12, 14, 19, 26, 58, 60, 55,
      14, 13, 16, 24, 40, 57, 69, 56,
      14, 17, 22, 29, 51, 87, 80, 62,
      18, 22, 37, 56, 68, 109, 103, 77,
      24, 35, 55, 64, 81, 104, 113, 92,
      49, 64, 78, 87, 103, 121, 120, 101,
      72, 92, 95, 98, 112, 100, 103, 99};
    const int CT[64] = {
      17, 18, 24, 47, 99, 99, 99, 99,
      18, 21, 26, 66, 99, 99, 99, 99,
      24, 26, 56, 99, 99, 99, 99, 99,
      47, 66, 99, 99, 99, 99, 99, 99,
      99, 99, 99, 99, 99, 99, 99, 99,
      99, 99, 99, 99, 99, 99, 99, 99,
      99, 99, 99, 99, 99, 99, 99, 99,
      99, 99, 99, 99, 99, 99, 99, 99};
    for (int i = 0; i < 64; ++i) {
      yq[i] = (float)YT[i];
      cq[i] = (float)CT[i];
    }
  }
};

}  // namespace jc

__constant__ jc::Tab TT;  // addrspace(4): uniform loads are true s_load SMEM

// ---- contraction-proof f32 ops (asm boundary blocks FMA formation) ----
__device__ __forceinline__ float vmul(float a, float b) {
  float r; asm("v_mul_f32 %0, %1, %2" : "=v"(r) : "v"(a), "v"(b)); return r;
}
__device__ __forceinline__ float vadd(float a, float b) {
  float r; asm("v_add_f32 %0, %1, %2" : "=v"(r) : "v"(a), "v"(b)); return r;
}
__device__ __forceinline__ float vsubf(float a, float b) {  // a - b
  float r; asm("v_sub_f32 %0, %1, %2" : "=v"(r) : "v"(a), "v"(b)); return r;
}

__device__ __forceinline__ float chro_t(float tR, float tG, float tB,
                                        float kR, float kG, float kB) {
  float a = vmul(tR, kR);
  a = vadd(a, vmul(tG, kG));
  a = vadd(a, vmul(tB, kB));
  return vadd(a, 128.0f);
}

// quantize: rintf( rn( rn(sc*acc) / q ) )  -- verified op sequence
__device__ __forceinline__ float q4(float acc, float sc, float q) {
  return rintf(__fdiv_rn(vmul(sc, acc), q));
}

// ================= mega-asm DCT machinery (pipelined, dual-output) ==========
// X block resident in v[40:103] (X_j <-> v(40+j)).
// SGPR bank A = s[36:67]: rowA chunk in s[36:51], rowB chunk in s[52:67].
// SGPR bank B = s[68:99]: rowA chunk in s[68:83], rowB chunk in s[84:99].
// Chunks (16 j each) alternate banks A,B,A,B; next chunk's loads are issued
// right after the wait, before the current chain -> latency hidden.
// v104/v105 = mul temps for the two interleaved output chains.

#define MAC4(AA, AB, SA, SB, XJ) \
  "v_mul_f32 v104, " SA ", " XJ "\n\t" \
  "v_mul_f32 v105, " SB ", " XJ "\n\t" \
  "v_add_f32 " AA ", " AA ", v104\n\t" \
  "v_add_f32 " AB ", " AB ", v105\n\t"

// chunk0, bank A, X v40-55, with acc init (rn(0+x)=x)
#define CH0I(AA, AB) \
  "v_mul_f32 " AA ", s36, v40\n\t" \
  "v_mul_f32 " AB ", s52, v40\n\t" \
  MAC4(AA,AB,"s37","s53","v41") MAC4(AA,AB,"s38","s54","v42") \
  MAC4(AA,AB,"s39","s55","v43") MAC4(AA,AB,"s40","s56","v44") \
  MAC4(AA,AB,"s41","s57","v45") MAC4(AA,AB,"s42","s58","v46") \
  MAC4(AA,AB,"s43","s59","v47") MAC4(AA,AB,"s44","s60","v48") \
  MAC4(AA,AB,"s45","s61","v49") MAC4(AA,AB,"s46","s62","v50") \
  MAC4(AA,AB,"s47","s63","v51") MAC4(AA,AB,"s48","s64","v52") \
  MAC4(AA,AB,"s49","s65","v53") MAC4(AA,AB,"s50","s66","v54") \
  MAC4(AA,AB,"s51","s67","v55")

// chunk1, bank B, X v56-71
#define CH1B(AA, AB) \
  MAC4(AA,AB,"s68","s84","v56") MAC4(AA,AB,"s69","s85","v57") \
  MAC4(AA,AB,"s70","s86","v58") MAC4(AA,AB,"s71","s87","v59") \
  MAC4(AA,AB,"s72","s88","v60") MAC4(AA,AB,"s73","s89","v61") \
  MAC4(AA,AB,"s74","s90","v62") MAC4(AA,AB,"s75","s91","v63") \
  MAC4(AA,AB,"s76","s92","v64") MAC4(AA,AB,"s77","s93","v65") \
  MAC4(AA,AB,"s78","s94","v66") MAC4(AA,AB,"s79","s95","v67") \
  MAC4(AA,AB,"s80","s96","v68") MAC4(AA,AB,"s81","s97","v69") \
  MAC4(AA,AB,"s82","s98","v70") MAC4(AA,AB,"s83","s99","v71")

// chunk2, bank A, X v72-87
#define CH2A(AA, AB) \
  MAC4(AA,AB,"s36","s52","v72") MAC4(AA,AB,"s37","s53","v73") \
  MAC4(AA,AB,"s38","s54","v74") MAC4(AA,AB,"s39","s55","v75") \
  MAC4(AA,AB,"s40","s56","v76") MAC4(AA,AB,"s41","s57","v77") \
  MAC4(AA,AB,"s42","s58","v78") MAC4(AA,AB,"s43","s59","v79") \
  MAC4(AA,AB,"s44","s60","v80") MAC4(AA,AB,"s45","s61","v81") \
  MAC4(AA,AB,"s46","s62","v82") MAC4(AA,AB,"s47","s63","v83") \
  MAC4(AA,AB,"s48","s64","v84") MAC4(AA,AB,"s49","s65","v85") \
  MAC4(AA,AB,"s50","s66","v86") MAC4(AA,AB,"s51","s67","v87")

// chunk3, bank B, X v88-103
#define CH3B(AA, AB) \
  MAC4(AA,AB,"s68","s84","v88") MAC4(AA,AB,"s69","s85","v89") \
  MAC4(AA,AB,"s70","s86","v90") MAC4(AA,AB,"s71","s87","v91") \
  MAC4(AA,AB,"s72","s88","v92") MAC4(AA,AB,"s73","s89","v93") \
  MAC4(AA,AB,"s74","s90","v94") MAC4(AA,AB,"s75","s91","v95") \
  MAC4(AA,AB,"s76","s92","v96") MAC4(AA,AB,"s77","s93","v97") \
  MAC4(AA,AB,"s78","s94","v98") MAC4(AA,AB,"s79","s95","v99") \
  MAC4(AA,AB,"s80","s96","v100") MAC4(AA,AB,"s81","s97","v101") \
  MAC4(AA,AB,"s82","s98","v102") MAC4(AA,AB,"s83","s99","v103")

// one output-pair (rows 2p, 2p+1): 4 chunks, prefetching one chunk ahead.
// O1*,O2*,O3* = this pair's chunk 1/2/3 offsets; ON* = next pair chunk 0.
#define PAIRP(AA, AB, O1A, O1B, O2A, O2B, O3A, O3B, ONA, ONB) \
  "s_waitcnt lgkmcnt(0)\n\t" \
  "s_load_dwordx16 s[68:83], %[tp], " O1A "\n\t" \
  "s_load_dwordx16 s[84:99], %[tp], " O1B "\n\t" \
  CH0I(AA, AB) \
  "s_waitcnt lgkmcnt(0)\n\t" \
  "s_load_dwordx16 s[36:51], %[tp], " O2A "\n\t" \
  "s_load_dwordx16 s[52:67], %[tp], " O2B "\n\t" \
  CH1B(AA, AB) \
  "s_waitcnt lgkmcnt(0)\n\t" \
  "s_load_dwordx16 s[68:83], %[tp], " O3A "\n\t" \
  "s_load_dwordx16 s[84:99], %[tp], " O3B "\n\t" \
  CH2A(AA, AB) \
  "s_waitcnt lgkmcnt(0)\n\t" \
  "s_load_dwordx16 s[36:51], %[tp], " ONA "\n\t" \
  "s_load_dwordx16 s[52:67], %[tp], " ONB "\n\t" \
  CH3B(AA, AB)

#define XLOAD \
  "ds_read_b128 v[40:43], %[xa] offset:0\n\t" \
  "ds_read_b128 v[44:47], %[xa] offset:16\n\t" \
  "ds_read_b128 v[48:51], %[xa] offset:32\n\t" \
  "ds_read_b128 v[52:55], %[xa] offset:48\n\t" \
  "ds_read_b128 v[56:59], %[xa] offset:64\n\t" \
  "ds_read_b128 v[60:63], %[xa] offset:80\n\t" \
  "ds_read_b128 v[64:67], %[xa] offset:96\n\t" \
  "ds_read_b128 v[68:71], %[xa] offset:112\n\t" \
  "ds_read_b128 v[72:75], %[xa] offset:128\n\t" \
  "ds_read_b128 v[76:79], %[xa] offset:144\n\t" \
  "ds_read_b128 v[80:83], %[xa] offset:160\n\t" \
  "ds_read_b128 v[84:87], %[xa] offset:176\n\t" \
  "ds_read_b128 v[88:91], %[xa] offset:192\n\t" \
  "ds_read_b128 v[92:95], %[xa] offset:208\n\t" \
  "ds_read_b128 v[96:99], %[xa] offset:224\n\t" \
  "ds_read_b128 v[100:103], %[xa] offset:240\n\t"

#define VCLOB \
  "v40","v41","v42","v43","v44","v45","v46","v47","v48","v49", \
  "v50","v51","v52","v53","v54","v55","v56","v57","v58","v59", \
  "v60","v61","v62","v63","v64","v65","v66","v67","v68","v69", \
  "v70","v71","v72","v73","v74","v75","v76","v77","v78","v79", \
  "v80","v81","v82","v83","v84","v85","v86","v87","v88","v89", \
  "v90","v91","v92","v93","v94","v95","v96","v97","v98","v99", \
  "v100","v101","v102","v103","v104","v105"

#define SCLOB \
  "s36","s37","s38","s39","s40","s41","s42","s43","s44","s45", \
  "s46","s47","s48","s49","s50","s51","s52","s53","s54","s55", \
  "s56","s57","s58","s59","s60","s61","s62","s63","s64","s65", \
  "s66","s67","s68","s69","s70","s71","s72","s73","s74","s75", \
  "s76","s77","s78","s79","s80","s81","s82","s83","s84","s85", \
  "s86","s87","s88","s89","s90","s91","s92","s93","s94","s95", \
  "s96","s97","s98","s99"

// one slab: 16 outputs (rows TP..TP+15 of T). Pair p -> outputs 2p, 2p+1.
// Last pair's ON* prefetch reads past the slab (max tp_byte+4352 <= 16640
// < sizeof(Tab)=17152) -- in-bounds, unused.
#define DCT16(AA, TPX) \
  asm volatile( \
    XLOAD \
    "s_load_dwordx16 s[36:51], %[tp], 0\n\t" \
    "s_load_dwordx16 s[52:67], %[tp], 256\n\t" \
    PAIRP("%[a0]","%[a1]",   "64","320","128","384","192","448","512","768") \
    PAIRP("%[a2]","%[a3]",   "576","832","640","896","704","960","1024","1280") \
    PAIRP("%[a4]","%[a5]",   "1088","1344","1152","1408","1216","1472","1536","1792") \
    PAIRP("%[a6]","%[a7]",   "1600","1856","1664","1920","1728","1984","2048","2304") \
    PAIRP("%[a8]","%[a9]",   "2112","2368","2176","2432","2240","2496","2560","2816") \
    PAIRP("%[a10]","%[a11]", "2624","2880","2688","2944","2752","3008","3072","3328") \
    PAIRP("%[a12]","%[a13]", "3136","3392","3200","3456","3264","3520","3584","3840") \
    PAIRP("%[a14]","%[a15]", "3648","3904","3712","3968","3776","4032","4096","4352") \
    : [a0]"=&v"(AA##0),  [a1]"=&v"(AA##1),  [a2]"=&v"(AA##2),  [a3]"=&v"(AA##3), \
      [a4]"=&v"(AA##4),  [a5]"=&v"(AA##5),  [a6]"=&v"(AA##6),  [a7]"=&v"(AA##7), \
      [a8]"=&v"(AA##8),  [a9]"=&v"(AA##9),  [a10]"=&v"(AA##10),[a11]"=&v"(AA##11), \
      [a12]"=&v"(AA##12),[a13]"=&v"(AA##13),[a14]"=&v"(AA##14),[a15]"=&v"(AA##15) \
    : [xa]"v"(xaddr), [tp]"s"(TPX) \
    : "memory", VCLOB, SCLOB)

// grid: 2048 wg x 256 thr. wg = 64x64-px region: 64 Y + 16 Cb + 16 Cr blocks.
// Phase 2: wave0/1 -> Y blocks (lane=block), i in [0,32)/[32,64);
//          wave2/3 -> chroma blocks 64+(lane&31) (lanes 0-31), same i split.
__global__ __launch_bounds__(256, 4)
void jpeg_kernel(const float* __restrict__ img, float* __restrict__ out) {
  __shared__ float LDSbuf[96 * 68];  // X region; slab overlays AFTER barrier 2

  const int t = threadIdx.x;
  const int lane = t & 63;
  const int w = __builtin_amdgcn_readfirstlane(t >> 6);  // uniform wave id
  const int wid = blockIdx.x;
  const int b = wid >> 6;   // batch 0..31
  const int r = wid & 63;   // region 0..63

  // ================= phase 1: merged staging (r8/r13/r14 verbatim) ==========
  {
    const int yb = t & 63;
    const int q = t >> 6;
    const int by = yb >> 3, bx = yb & 7;
    const int prow = (r >> 3) * 64 + by * 8 + 2 * q;
    const int pcol = (r & 7) * 64 + bx * 8;
    const float* rp = img + (size_t)b * 786432 + (size_t)prow * 512 + pcol;

    float tv[3][2][8];
#pragma unroll
    for (int c = 0; c < 3; ++c) {
#pragma unroll
      for (int rr = 0; rr < 2; ++rr) {
        const float* p0 = rp + c * 262144 + rr * 512;
        const float4 va = *(const float4*)(p0);
        const float4 vb = *(const float4*)(p0 + 4);
        tv[c][rr][0] = vmul(va.x, 255.0f);
        tv[c][rr][1] = vmul(va.y, 255.0f);
        tv[c][rr][2] = vmul(va.z, 255.0f);
        tv[c][rr][3] = vmul(va.w, 255.0f);
        tv[c][rr][4] = vmul(vb.x, 255.0f);
        tv[c][rr][5] = vmul(vb.y, 255.0f);
        tv[c][rr][6] = vmul(vb.z, 255.0f);
        tv[c][rr][7] = vmul(vb.w, 255.0f);
      }
    }
#pragma unroll
    for (int rr = 0; rr < 2; ++rr) {
#pragma unroll
      for (int y = 0; y < 8; ++y) {
        float a = vmul(tv[0][rr][y], 0.299f);
        a = vadd(a, vmul(tv[1][rr][y], 0.587f));
        a = vadd(a, vmul(tv[2][rr][y], 0.114f));
        LDSbuf[yb * 68 + 16 * q + rr * 8 + y] = vsubf(a, 128.0f);
      }
    }
    const int lcr = 4 * by + q;
#pragma unroll
    for (int pc = 0; pc < 4; ++pc) {
      const int lcc = 4 * bx + pc;
      const int crow = 64 + ((lcr >> 3) * 4 + (lcc >> 3));
      const int cell = (lcr & 7) * 8 + (lcc & 7);
      const int e = 2 * pc, o = 2 * pc + 1;
      {
        const float p00 = chro_t(tv[0][0][e], tv[1][0][e], tv[2][0][e], -0.168736f, -0.331264f, 0.5f);
        const float p01 = chro_t(tv[0][0][o], tv[1][0][o], tv[2][0][o], -0.168736f, -0.331264f, 0.5f);
        const float p10 = chro_t(tv[0][1][e], tv[1][1][e], tv[2][1][e], -0.168736f, -0.331264f, 0.5f);
        const float p11 = chro_t(tv[0][1][o], tv[1][1][o], tv[2][1][o], -0.168736f, -0.331264f, 0.5f);
        const float s = vadd(vadd(vadd(p00, p01), p10), p11);
        LDSbuf[crow * 68 + cell] = vsubf(vmul(s, 0.25f), 128.0f);
      }
      {
        const float p00 = chro_t(tv[0][0][e], tv[1][0][e], tv[2][0][e], 0.5f, -0.418688f, -0.081312f);
        const float p01 = chro_t(tv[0][0][o], tv[1][0][o], tv[2][0][o], 0.5f, -0.418688f, -0.081312f);
        const float p10 = chro_t(tv[0][1][e], tv[1][1][e], tv[2][1][e], 0.5f, -0.418688f, -0.081312f);
        const float p11 = chro_t(tv[0][1][o], tv[1][1][o], tv[2][1][o], 0.5f, -0.418688f, -0.081312f);
        const float s = vadd(vadd(vadd(p00, p01), p10), p11);
        LDSbuf[(crow + 16) * 68 + cell] = vsubf(vmul(s, 0.25f), 128.0f);
      }
    }
  }

  // ================= phase 2: pipelined mega-asm DCT =================
  const int ibase = (w & 1) * 32;
  const bool chro = (w >= 2);
  const bool active = (!chro) || (lane < 32);
  const int blk = chro ? (64 + (lane & 31)) : lane;
  const float* qt = chro ? TT.cq : TT.yq;  // uniform (constant AS)

  const unsigned xaddr = (unsigned)(size_t)(&LDSbuf[blk * 68]);
  const float* tp0 = TT.tr + (size_t)(ibase) * 64;        // slab f=0 rows
  const float* tp1 = TT.tr + (size_t)(ibase + 16) * 64;   // slab f=1 rows

  float aa0, aa1, aa2, aa3, aa4, aa5, aa6, aa7;
  float aa8, aa9, aa10, aa11, aa12, aa13, aa14, aa15;
  float bb0, bb1, bb2, bb3, bb4, bb5, bb6, bb7;
  float bb8, bb9, bb10, bb11, bb12, bb13, bb14, bb15;

  __syncthreads();  // staging complete

  if (active) {
    DCT16(aa, tp0);
    DCT16(bb, tp1);
  }

  __syncthreads();  // all X reads done; LDSbuf reusable as transpose slab

  const int ybase = b * 4096 + (r >> 3) * 512 + (r & 7) * 8;
  const int cbase = b * 1024 + (r >> 3) * 128 + (r & 7) * 4;

#define QSTORE(A, B, C, D, G, CO) do { \
    float4 v4_; \
    v4_.x = q4(A, TT.sc[(CO) + 4*(G) + 0], qt[(CO) + 4*(G) + 0]); \
    v4_.y = q4(B, TT.sc[(CO) + 4*(G) + 1], qt[(CO) + 4*(G) + 1]); \
    v4_.z = q4(C, TT.sc[(CO) + 4*(G) + 2], qt[(CO) + 4*(G) + 2]); \
    v4_.w = q4(D, TT.sc[(CO) + 4*(G) + 3], qt[(CO) + 4*(G) + 3]); \
    *(float4*)&LDSbuf[(w * 64 + lane) * 20 + 4*(G)] = v4_; \
  } while (0)

  // ---- slab f=0 (coeffs ibase .. ibase+15) ----
  {
    const int co = ibase;
    if (active) {
      QSTORE(aa0,  aa1,  aa2,  aa3,  0, co);
      QSTORE(aa4,  aa5,  aa6,  aa7,  1, co);
      QSTORE(aa8,  aa9,  aa10, aa11, 2, co);
      QSTORE(aa12, aa13, aa14, aa15, 3, co);
    }
    if (!chro) {
#pragma unroll
      for (int k = 0; k < 4; ++k) {
        const int B = k * 16 + (lane >> 2);
        const int e0 = (lane & 3) * 4;
        const float4 vv = *(const float4*)&LDSbuf[(w * 64 + B) * 20 + e0];
        const unsigned ob = (unsigned)(ybase + (B >> 3) * 64 + (B & 7));
        *(float4*)&out[(ob << 6) + (unsigned)(co + e0)] = vv;
      }
    } else {
#pragma unroll
      for (int k = 0; k < 2; ++k) {
        const int idx = k * 64 + lane;
        const int B = idx >> 2;
        const int e0 = (idx & 3) * 4;
        const float4 vv = *(const float4*)&LDSbuf[(w * 64 + B) * 20 + e0];
        const int cc = B & 15;
        const unsigned ob = 8388608u + (B >= 16 ? 2097152u : 0u) +
            (((unsigned)(cbase + (cc >> 2) * 32 + (cc & 3))) << 6);
        *(float4*)&out[ob + (unsigned)(co + e0)] = vv;
      }
    }
  }

  // ---- slab f=1 (coeffs ibase+16 .. ibase+31) ----
  {
    const int co = ibase + 16;
    if (active) {
      QSTORE(bb0,  bb1,  bb2,  bb3,  0, co);
      QSTORE(bb4,  bb5,  bb6,  bb7,  1, co);
      QSTORE(bb8,  bb9,  bb10, bb11, 2, co);
      QSTORE(bb12, bb13, bb14, bb15, 3, co);
    }
    if (!chro) {
#pragma unroll
      for (int k = 0; k < 4; ++k) {
        const int B = k * 16 + (lane >> 2);
        const int e0 = (lane & 3) * 4;
        const float4 vv = *(const float4*)&LDSbuf[(w * 64 + B) * 20 + e0];
        const unsigned ob = (unsigned)(ybase + (B >> 3) * 64 + (B & 7));
        *(float4*)&out[(ob << 6) + (unsigned)(co + e0)] = vv;
      }
    } else {
#pragma unroll
      for (int k = 0; k < 2; ++k) {
        const int idx = k * 64 + lane;
        const int B = idx >> 2;
        const int e0 = (idx & 3) * 4;
        const float4 vv = *(const float4*)&LDSbuf[(w * 64 + B) * 20 + e0];
        const int cc = B & 15;
        const unsigned ob = 8388608u + (B >= 16 ? 2097152u : 0u) +
            (((unsigned)(cbase + (cc >> 2) * 32 + (cc & 3))) << 6);
        *(float4*)&out[ob + (unsigned)(co + e0)] = vv;
      }
    }
  }
#undef QSTORE
}

extern "C" void kernel_launch(void* const* d_in, const int* in_sizes, int n_in,
                              void* d_out, int out_size, void* d_ws, size_t ws_size,
                              hipStream_t stream) {
  (void)in_sizes; (void)n_in; (void)d_ws; (void)ws_size; (void)out_size;
  const float* img = (const float*)d_in[0];
  float* out = (float*)d_out;
  jpeg_kernel<<<dim3(2048), dim3(256), 0, stream>>>(img, out);
}